// Round 4
// baseline (169.332 us; speedup 1.0000x reference)
//
#include <hip/hip_runtime.h>

// Swin window attention, MI355X gfx950. Block = one 8x8 window; 512 thr = 8 waves; wave w owns head w.
// All GEMMs bf16 MFMA 16x16x32 with operand-swap-chosen C layouts so every LDS write is a packed 8B/16B op.
// P (attention probs) never touches LDS: V's j-rows are permuted to match the lane-local P fragment.
// LDS 33 KB: [0,32768) = x window bf16 (GEMM1 A), then reused as 8 x 4KB per-wave slices (q->k->v_t->ao
// time-multiplexed; same-wave DS ops are in-order). peg[225] f32 @32768.

typedef __attribute__((ext_vector_type(8))) short bf16x8;
typedef __attribute__((ext_vector_type(4))) float f32x4;

#define MFMA16(a,b,c) __builtin_amdgcn_mfma_f32_16x16x32_bf16(a,b,c,0,0,0)
#define SCALE 0.17677669529663687f
#define WS_QKV_BYTES 393216
#define WS_TOTAL_BYTES 524288
#define PEG_OFF 32768

__device__ __forceinline__ short bfr(float f) {          // f32 -> bf16 bits (RNE), fallback path
    unsigned u = __builtin_bit_cast(unsigned, f);
    u = (u + 0x7FFFu + ((u >> 16) & 1u)) >> 16;
    return (short)u;
}
__device__ __forceinline__ unsigned pkbf(float lo, float hi) {   // 2x f32 -> packed bf16x2 (HW RNE)
    unsigned r;
    asm("v_cvt_pk_bf16_f32 %0, %1, %2" : "=v"(r) : "v"(lo), "v"(hi));
    return r;
}

__device__ __forceinline__ bf16x8 cvt8(const float* gp) {
    float4 f0 = *reinterpret_cast<const float4*>(gp);
    float4 f1 = *reinterpret_cast<const float4*>(gp + 4);
    float fv[8] = {f0.x,f0.y,f0.z,f0.w,f1.x,f1.y,f1.z,f1.w};
    bf16x8 r;
    #pragma unroll
    for (int j = 0; j < 8; ++j) r[j] = bfr(fv[j]);
    return r;
}

// Pre-fragment weights to bf16. Fragment f = oblk*8 + kk holds 1 KB:
// lane (lg,ln) 16B at f*1024 + (lg*16+ln)*16 = elems (o = oblk*16+ln, k = kk*32+lg*8+e).
__global__ void prep_kernel(const float* __restrict__ wqkv, const float* __restrict__ wout,
                            char* __restrict__ ws) {
    int t = blockIdx.x * 256 + threadIdx.x;      // 32768 threads, 8 elems each
    const float* src;
    int byt;
    if (t < 24576) {                              // wqkv: 768 x 256
        int o = t >> 5, kc = t & 31;
        src = wqkv + o * 256 + kc * 8;
        byt = ((o >> 4) * 8 + (kc >> 2)) * 1024 + ((kc & 3) * 16 + (o & 15)) * 16;
    } else {                                      // wout: 256 x 256
        int t2 = t - 24576;
        int o = t2 >> 5, kc = t2 & 31;
        src = wout + o * 256 + kc * 8;
        byt = WS_QKV_BYTES + ((o >> 4) * 8 + (kc >> 2)) * 1024 + ((kc & 3) * 16 + (o & 15)) * 16;
    }
    *reinterpret_cast<bf16x8*>(ws + byt) = cvt8(src);
}

template<bool USE_WS>
__global__ __launch_bounds__(512, 2)
void winattn_kernel(const float* __restrict__ x, const float* __restrict__ wqkv,
                    const float* __restrict__ peg, const float* __restrict__ wout,
                    const float* __restrict__ bout, float* __restrict__ out,
                    const char* __restrict__ wsb)
{
    __shared__ __align__(16) char lds[33792];
    const int tid = threadIdx.x;
    const int wave = tid >> 6, lane = tid & 63;
    const int lg = lane >> 4, ln = lane & 15;
    const int img = blockIdx.x >> 8, win = blockIdx.x & 255;
    const size_t base = ((size_t)(img * 128 + (win >> 4) * 8) * 128 + (win & 15) * 8) * 256;
    const int lswz = (ln & 7) << 4;

    // ---------- Phase 0: stage x window bf16 (swizzled, cvt_pk) + peg ----------
    #pragma unroll
    for (int i = 0; i < 4; ++i) {
        int ch = tid + i * 512;                    // 2048 chunks of 8 floats
        int t = ch >> 5, cc = ch & 31;
        const float* gp = x + base + (size_t)(((t >> 3) * 128 + (t & 7)) * 256 + cc * 8);
        float4 f0 = *reinterpret_cast<const float4*>(gp);
        float4 f1 = *reinterpret_cast<const float4*>(gp + 4);
        int4 w;
        w.x = (int)pkbf(f0.x, f0.y); w.y = (int)pkbf(f0.z, f0.w);
        w.z = (int)pkbf(f1.x, f1.y); w.w = (int)pkbf(f1.z, f1.w);
        *reinterpret_cast<int4*>(lds + ((t * 512 + cc * 16) ^ ((t & 7) << 4))) = w;
    }
    if (tid < 225) ((float*)(lds + PEG_OFF))[tid] = peg[tid];
    __syncthreads();

    // ---------- GEMM1: q,k tiles swapped (D[o][t]), v tiles normal (D[t][d]) ----------
    f32x4 aqk[4][4];   // q,k: rows o = nv*16+lg*4+r (nv 0..3), cols t = mt*16+ln
    f32x4 av[4][2];    // v:   rows t = mt*16+lg*4+r, cols d = u*16+ln
    #pragma unroll
    for (int a = 0; a < 4; ++a) {
        #pragma unroll
        for (int b = 0; b < 4; ++b) aqk[a][b] = (f32x4){0.f,0.f,0.f,0.f};
        #pragma unroll
        for (int b = 0; b < 2; ++b) av[a][b] = (f32x4){0.f,0.f,0.f,0.f};
    }
    const int fl = (lg * 16 + ln) * 16;
    #pragma unroll 1
    for (int kk = 0; kk < 8; ++kk) {
        bf16x8 ah[4];
        #pragma unroll
        for (int mt = 0; mt < 4; ++mt)
            ah[mt] = *reinterpret_cast<const bf16x8*>(
                lds + (((mt * 16 + ln) * 512 + kk * 64 + lg * 16) ^ lswz));
        #pragma unroll
        for (int nv = 0; nv < 6; ++nv) {
            bf16x8 bh;
            if constexpr (USE_WS) {
                bh = *reinterpret_cast<const bf16x8*>(
                    wsb + (((nv >> 1) * 16 + wave * 2 + (nv & 1)) * 8 + kk) * 1024 + fl);
            } else {
                int o = (nv >> 1) * 256 + wave * 32 + (nv & 1) * 16 + ln;
                bh = cvt8(wqkv + (size_t)o * 256 + kk * 32 + lg * 8);
            }
            if (nv < 4) {
                #pragma unroll
                for (int mt = 0; mt < 4; ++mt)
                    aqk[mt][nv] = MFMA16(bh, ah[mt], aqk[mt][nv]);   // swapped: D[o][t]
            } else {
                #pragma unroll
                for (int mt = 0; mt < 4; ++mt)
                    av[mt][nv - 4] = MFMA16(ah[mt], bh, av[mt][nv - 4]);  // normal: D[t][d]
            }
        }
    }
    __syncthreads();   // x dead; per-wave 4KB slices live

    char* slc = lds + wave * 4096;

    // ---------- q -> LDS [t][32d] packed, read aq ----------
    #pragma unroll
    for (int mt = 0; mt < 4; ++mt)
        #pragma unroll
        for (int u = 0; u < 2; ++u) {
            int lin = (mt * 16 + ln) * 64 + u * 32 + lg * 8;
            uint2 w = make_uint2(pkbf(aqk[mt][u][0], aqk[mt][u][1]),
                                 pkbf(aqk[mt][u][2], aqk[mt][u][3]));
            *reinterpret_cast<uint2*>(slc + (lin ^ lswz)) = w;
        }
    bf16x8 aq[4];
    #pragma unroll
    for (int mi = 0; mi < 4; ++mi)
        aq[mi] = *reinterpret_cast<const bf16x8*>(slc + ((((mi * 16 + ln) * 64) + lg * 16) ^ lswz));

    // ---------- k -> same region (q consumed), read bk ----------
    #pragma unroll
    for (int mt = 0; mt < 4; ++mt)
        #pragma unroll
        for (int u = 0; u < 2; ++u) {
            int lin = (mt * 16 + ln) * 64 + u * 32 + lg * 8;
            uint2 w = make_uint2(pkbf(aqk[mt][2 + u][0], aqk[mt][2 + u][1]),
                                 pkbf(aqk[mt][2 + u][2], aqk[mt][2 + u][3]));
            *reinterpret_cast<uint2*>(slc + (lin ^ lswz)) = w;
        }
    bf16x8 bk[4];
    #pragma unroll
    for (int nj = 0; nj < 4; ++nj)
        bk[nj] = *reinterpret_cast<const bf16x8*>(slc + ((((nj * 16 + ln) * 64) + lg * 16) ^ lswz));

    // ---------- v^T -> same region [32d][64t] packed (k consumed) ----------
    #pragma unroll
    for (int mt = 0; mt < 4; ++mt)
        #pragma unroll
        for (int u = 0; u < 2; ++u) {
            int d = u * 16 + ln;
            int lin = d * 128 + mt * 32 + lg * 8;
            uint2 w = make_uint2(pkbf(av[mt][u][0], av[mt][u][1]),
                                 pkbf(av[mt][u][2], av[mt][u][3]));
            *reinterpret_cast<uint2*>(slc + (lin ^ lswz)) = w;
        }

    // ---------- QK^T swapped: sc[mi][nj] = K_nj x Q_mi -> D[j][m], lane owns row m=mi*16+ln ----------
    f32x4 sc[4][4];
    #pragma unroll
    for (int mi = 0; mi < 4; ++mi)
        #pragma unroll
        for (int nj = 0; nj < 4; ++nj)
            sc[mi][nj] = MFMA16(bk[nj], aq[mi], ((f32x4){0.f,0.f,0.f,0.f}));

    // bias base: idx = A0 + 30*(nj-mi) + r, addr = peg + 4*idx (immediate offsets after unroll)
    const char* bp = lds + PEG_OFF - 360 +
        4 * ((((lg >> 1) - (ln >> 3) + 7) * 15) + (lg & 1) * 4 - (ln & 7) + 7);

    float pinv[4];
    bf16x8 ap[4][2];
    #pragma unroll
    for (int mi = 0; mi < 4; ++mi) {
        #pragma unroll
        for (int nj = 0; nj < 4; ++nj)
            #pragma unroll
            for (int r = 0; r < 4; ++r)
                sc[mi][nj][r] = fmaf(sc[mi][nj][r], SCALE,
                    *reinterpret_cast<const float*>(bp + 360 + 120 * (nj - mi) + 4 * r));
        float mx = sc[mi][0][0];
        #pragma unroll
        for (int nj = 0; nj < 4; ++nj)
            #pragma unroll
            for (int r = 0; r < 4; ++r) mx = fmaxf(mx, sc[mi][nj][r]);
        mx = fmaxf(mx, __shfl_xor(mx, 16));
        mx = fmaxf(mx, __shfl_xor(mx, 32));
        float sum = 0.f;
        #pragma unroll
        for (int nj = 0; nj < 4; ++nj)
            #pragma unroll
            for (int r = 0; r < 4; ++r) {
                float e = __expf(sc[mi][nj][r] - mx);
                sc[mi][nj][r] = e;
                sum += e;
            }
        sum += __shfl_xor(sum, 16);
        sum += __shfl_xor(sum, 32);
        pinv[mi] = 1.f / sum;
        // pack unnormalized P fragments (j permuted: slot (lg,e) = 32kkv+16(e>>2)+4lg+(e&3))
        #pragma unroll
        for (int kkv = 0; kkv < 2; ++kkv) {
            int4 t;
            t.x = (int)pkbf(sc[mi][2 * kkv][0],     sc[mi][2 * kkv][1]);
            t.y = (int)pkbf(sc[mi][2 * kkv][2],     sc[mi][2 * kkv][3]);
            t.z = (int)pkbf(sc[mi][2 * kkv + 1][0], sc[mi][2 * kkv + 1][1]);
            t.w = (int)pkbf(sc[mi][2 * kkv + 1][2], sc[mi][2 * kkv + 1][3]);
            ap[mi][kkv] = __builtin_bit_cast(bf16x8, t);
        }
    }

    // ---------- PV swapped: po[u][mi] = V^T x P^T -> D[d][m]; V rows j-permuted to match ap ----------
    f32x4 po[2][4];
    #pragma unroll
    for (int u = 0; u < 2; ++u)
        #pragma unroll
        for (int mi = 0; mi < 4; ++mi) po[u][mi] = (f32x4){0.f,0.f,0.f,0.f};
    #pragma unroll
    for (int kkv = 0; kkv < 2; ++kkv) {
        bf16x8 bvf[2];
        #pragma unroll
        for (int u = 0; u < 2; ++u) {
            int d = u * 16 + ln;
            int lin0 = d * 128 + kkv * 64 + lg * 8;
            uint2 lo = *reinterpret_cast<const uint2*>(slc + (lin0 ^ lswz));
            uint2 hi = *reinterpret_cast<const uint2*>(slc + ((lin0 + 32) ^ lswz));
            int4 t; t.x = (int)lo.x; t.y = (int)lo.y; t.z = (int)hi.x; t.w = (int)hi.y;
            bvf[u] = __builtin_bit_cast(bf16x8, t);
        }
        #pragma unroll
        for (int u = 0; u < 2; ++u)
            #pragma unroll
            for (int mi = 0; mi < 4; ++mi)
                po[u][mi] = MFMA16(bvf[u], ap[mi][kkv], po[u][mi]);
    }

    // ---------- ao -> slice [t][32d] packed (v dead), normalized by pinv ----------
    #pragma unroll
    for (int u = 0; u < 2; ++u)
        #pragma unroll
        for (int mi = 0; mi < 4; ++mi) {
            int lin = (mi * 16 + ln) * 64 + u * 32 + lg * 8;
            uint2 w = make_uint2(pkbf(po[u][mi][0] * pinv[mi], po[u][mi][1] * pinv[mi]),
                                 pkbf(po[u][mi][2] * pinv[mi], po[u][mi][3] * pinv[mi]));
            *reinterpret_cast<uint2*>(slc + (lin ^ lswz)) = w;
        }
    __syncthreads();   // all waves' attn_out visible

    // ---------- GEMM2: out[64][32 cols of this wave] = AO[64][256] @ Wout^T + b ----------
    f32x4 fo[4][2];
    #pragma unroll
    for (int mi = 0; mi < 4; ++mi)
        #pragma unroll
        for (int u = 0; u < 2; ++u) fo[mi][u] = (f32x4){0.f,0.f,0.f,0.f};
    float bo0 = bout[wave * 32 + ln];
    float bo1 = bout[wave * 32 + 16 + ln];

    #pragma unroll 1
    for (int hh = 0; hh < 8; ++hh) {
        const char* ahh = lds + hh * 4096;
        bf16x8 aa[4];
        #pragma unroll
        for (int mi = 0; mi < 4; ++mi)
            aa[mi] = *reinterpret_cast<const bf16x8*>(ahh + ((((mi * 16 + ln) * 64) + lg * 16) ^ lswz));
        bf16x8 bb[2];
        #pragma unroll
        for (int u = 0; u < 2; ++u) {
            if constexpr (USE_WS) {
                bb[u] = *reinterpret_cast<const bf16x8*>(
                    wsb + WS_QKV_BYTES + ((wave * 2 + u) * 8 + hh) * 1024 + fl);
            } else {
                int oc = wave * 32 + u * 16 + ln;
                bb[u] = cvt8(wout + (size_t)oc * 256 + hh * 32 + lg * 8);
            }
        }
        #pragma unroll
        for (int mi = 0; mi < 4; ++mi)
            #pragma unroll
            for (int u = 0; u < 2; ++u)
                fo[mi][u] = MFMA16(aa[mi], bb[u], fo[mi][u]);
    }

    #pragma unroll
    for (int mi = 0; mi < 4; ++mi)
        #pragma unroll
        for (int r = 0; r < 4; ++r) {
            int t = mi * 16 + lg * 4 + r;
            float* op = out + base + (size_t)(((t >> 3) * 128 + (t & 7)) * 256);
            op[wave * 32 + ln]      = fo[mi][0][r] + bo0;
            op[wave * 32 + 16 + ln] = fo[mi][1][r] + bo1;
        }
}

extern "C" void kernel_launch(void* const* d_in, const int* in_sizes, int n_in,
                              void* d_out, int out_size, void* d_ws, size_t ws_size,
                              hipStream_t stream) {
    const float* x    = (const float*)d_in[0];
    const float* wqkv = (const float*)d_in[1];
    const float* peg  = (const float*)d_in[2];
    const float* wout = (const float*)d_in[3];
    const float* bout = (const float*)d_in[4];
    float* out = (float*)d_out;
    if (d_ws != nullptr && ws_size >= WS_TOTAL_BYTES) {
        hipLaunchKernelGGL(prep_kernel, dim3(128), dim3(256), 0, stream,
                           wqkv, wout, (char*)d_ws);
        hipLaunchKernelGGL((winattn_kernel<true>), dim3(2048), dim3(512), 0, stream,
                           x, wqkv, peg, wout, bout, out, (const char*)d_ws);
    } else {
        hipLaunchKernelGGL((winattn_kernel<false>), dim3(2048), dim3(512), 0, stream,
                           x, wqkv, peg, wout, bout, out, nullptr);
    }
}

// Round 5
// 125.682 us; speedup vs baseline: 1.3473x; 1.3473x over previous
//
#include <hip/hip_runtime.h>

// Swin window attention, MI355X gfx950. Block = one 8x8 window; 512 thr = 8 waves; wave w owns head w.
// All GEMMs bf16 MFMA 16x16x32 with operand-swap-chosen C layouts so every LDS write is a packed 8B/16B op.
// P (attention probs) never touches LDS: V's j-rows are permuted to match the lane-local P fragment.
// LDS 65 KB: [0,32768) = x window bf16 (GEMM1 A), then (after barrier) [0,65536) = 8 x 8KB per-wave
// slices: q@0 / k@+4096; v_t overlays q, ao overlays k (same-wave DS is in-order). peg[225] f32 @65536.

typedef __attribute__((ext_vector_type(8))) short bf16x8;
typedef __attribute__((ext_vector_type(4))) float f32x4;

#define MFMA16(a,b,c) __builtin_amdgcn_mfma_f32_16x16x32_bf16(a,b,c,0,0,0)
#define SCALE 0.17677669529663687f
#define WS_QKV_BYTES 393216
#define WS_TOTAL_BYTES 524288
#define PEG_OFF 65536

__device__ __forceinline__ short bfr(float f) {          // f32 -> bf16 bits (RNE), fallback path
    unsigned u = __builtin_bit_cast(unsigned, f);
    u = (u + 0x7FFFu + ((u >> 16) & 1u)) >> 16;
    return (short)u;
}
__device__ __forceinline__ unsigned pkbf(float lo, float hi) {   // 2x f32 -> packed bf16x2 (HW RNE)
    unsigned r;
    asm("v_cvt_pk_bf16_f32 %0, %1, %2" : "=v"(r) : "v"(lo), "v"(hi));
    return r;
}

__device__ __forceinline__ bf16x8 cvt8(const float* gp) {
    float4 f0 = *reinterpret_cast<const float4*>(gp);
    float4 f1 = *reinterpret_cast<const float4*>(gp + 4);
    float fv[8] = {f0.x,f0.y,f0.z,f0.w,f1.x,f1.y,f1.z,f1.w};
    bf16x8 r;
    #pragma unroll
    for (int j = 0; j < 8; ++j) r[j] = bfr(fv[j]);
    return r;
}

// Pre-fragment weights to bf16. Fragment f = oblk*8 + kk holds 1 KB:
// lane (lg,ln) 16B at f*1024 + (lg*16+ln)*16 = elems (o = oblk*16+ln, k = kk*32+lg*8+e).
__global__ void prep_kernel(const float* __restrict__ wqkv, const float* __restrict__ wout,
                            char* __restrict__ ws) {
    int t = blockIdx.x * 256 + threadIdx.x;      // 32768 threads, 8 elems each
    const float* src;
    int byt;
    if (t < 24576) {                              // wqkv: 768 x 256
        int o = t >> 5, kc = t & 31;
        src = wqkv + o * 256 + kc * 8;
        byt = ((o >> 4) * 8 + (kc >> 2)) * 1024 + ((kc & 3) * 16 + (o & 15)) * 16;
    } else {                                      // wout: 256 x 256
        int t2 = t - 24576;
        int o = t2 >> 5, kc = t2 & 31;
        src = wout + o * 256 + kc * 8;
        byt = WS_QKV_BYTES + ((o >> 4) * 8 + (kc >> 2)) * 1024 + ((kc & 3) * 16 + (o & 15)) * 16;
    }
    *reinterpret_cast<bf16x8*>(ws + byt) = cvt8(src);
}

template<bool USE_WS>
__global__ __launch_bounds__(512, 4)
void winattn_kernel(const float* __restrict__ x, const float* __restrict__ wqkv,
                    const float* __restrict__ peg, const float* __restrict__ wout,
                    const float* __restrict__ bout, float* __restrict__ out,
                    const char* __restrict__ wsb)
{
    __shared__ __align__(16) char lds[66560];
    const int tid = threadIdx.x;
    const int wave = tid >> 6, lane = tid & 63;
    const int lg = lane >> 4, ln = lane & 15;
    const int img = blockIdx.x >> 8, win = blockIdx.x & 255;
    const size_t base = ((size_t)(img * 128 + (win >> 4) * 8) * 128 + (win & 15) * 8) * 256;
    const int lswz = (ln & 7) << 4;

    // ---------- Phase 0: stage x window bf16 (swizzled, cvt_pk) + peg ----------
    #pragma unroll
    for (int i = 0; i < 4; ++i) {
        int ch = tid + i * 512;                    // 2048 chunks of 8 floats
        int t = ch >> 5, cc = ch & 31;
        const float* gp = x + base + (size_t)(((t >> 3) * 128 + (t & 7)) * 256 + cc * 8);
        float4 f0 = *reinterpret_cast<const float4*>(gp);
        float4 f1 = *reinterpret_cast<const float4*>(gp + 4);
        int4 w;
        w.x = (int)pkbf(f0.x, f0.y); w.y = (int)pkbf(f0.z, f0.w);
        w.z = (int)pkbf(f1.x, f1.y); w.w = (int)pkbf(f1.z, f1.w);
        *reinterpret_cast<int4*>(lds + ((t * 512 + cc * 16) ^ ((t & 7) << 4))) = w;
    }
    if (tid < 225) ((float*)(lds + PEG_OFF))[tid] = peg[tid];
    __syncthreads();

    // ---------- GEMM1: q,k tiles swapped (D[o][t]), v tiles normal (D[t][d]) ----------
    f32x4 aqk[4][4];   // q,k: rows o = nv*16+lg*4+r (nv 0..3), cols t = mt*16+ln
    f32x4 av[4][2];    // v:   rows t = mt*16+lg*4+r, cols d = u*16+ln
    #pragma unroll
    for (int a = 0; a < 4; ++a) {
        #pragma unroll
        for (int b = 0; b < 4; ++b) aqk[a][b] = (f32x4){0.f,0.f,0.f,0.f};
        #pragma unroll
        for (int b = 0; b < 2; ++b) av[a][b] = (f32x4){0.f,0.f,0.f,0.f};
    }
    const int fl = (lg * 16 + ln) * 16;
    #pragma unroll 1
    for (int kk = 0; kk < 8; ++kk) {
        bf16x8 ah[4];
        #pragma unroll
        for (int mt = 0; mt < 4; ++mt)
            ah[mt] = *reinterpret_cast<const bf16x8*>(
                lds + (((mt * 16 + ln) * 512 + kk * 64 + lg * 16) ^ lswz));
        #pragma unroll
        for (int nv = 0; nv < 6; ++nv) {
            bf16x8 bh;
            if constexpr (USE_WS) {
                bh = *reinterpret_cast<const bf16x8*>(
                    wsb + (((nv >> 1) * 16 + wave * 2 + (nv & 1)) * 8 + kk) * 1024 + fl);
            } else {
                int o = (nv >> 1) * 256 + wave * 32 + (nv & 1) * 16 + ln;
                bh = cvt8(wqkv + (size_t)o * 256 + kk * 32 + lg * 8);
            }
            if (nv < 4) {
                #pragma unroll
                for (int mt = 0; mt < 4; ++mt)
                    aqk[mt][nv] = MFMA16(bh, ah[mt], aqk[mt][nv]);   // swapped: D[o][t]
            } else {
                #pragma unroll
                for (int mt = 0; mt < 4; ++mt)
                    av[mt][nv - 4] = MFMA16(ah[mt], bh, av[mt][nv - 4]);  // normal: D[t][d]
            }
        }
    }
    __syncthreads();   // x dead; per-wave 8KB slices live

    char* slc = lds + wave * 8192;

    // ---------- q -> slc [t][32d], k -> slc+4096 (disjoint: one wait, then read both) ----------
    #pragma unroll
    for (int mt = 0; mt < 4; ++mt)
        #pragma unroll
        for (int u = 0; u < 2; ++u) {
            int lin = (mt * 16 + ln) * 64 + u * 32 + lg * 8;
            uint2 wq = make_uint2(pkbf(aqk[mt][u][0], aqk[mt][u][1]),
                                  pkbf(aqk[mt][u][2], aqk[mt][u][3]));
            uint2 wk = make_uint2(pkbf(aqk[mt][2 + u][0], aqk[mt][2 + u][1]),
                                  pkbf(aqk[mt][2 + u][2], aqk[mt][2 + u][3]));
            *reinterpret_cast<uint2*>(slc + (lin ^ lswz)) = wq;
            *reinterpret_cast<uint2*>(slc + 4096 + (lin ^ lswz)) = wk;
        }
    bf16x8 aq[4], bk[4];
    #pragma unroll
    for (int mi = 0; mi < 4; ++mi) {
        int lin = ((mi * 16 + ln) * 64 + lg * 16) ^ lswz;
        aq[mi] = *reinterpret_cast<const bf16x8*>(slc + lin);
        bk[mi] = *reinterpret_cast<const bf16x8*>(slc + 4096 + lin);
    }

    // ---------- v^T -> slc [32d][64t] (overlays q; same-wave DS in-order, aq reads precede) ----------
    #pragma unroll
    for (int mt = 0; mt < 4; ++mt)
        #pragma unroll
        for (int u = 0; u < 2; ++u) {
            int d = u * 16 + ln;
            int lin = d * 128 + mt * 32 + lg * 8;
            uint2 w = make_uint2(pkbf(av[mt][u][0], av[mt][u][1]),
                                 pkbf(av[mt][u][2], av[mt][u][3]));
            *reinterpret_cast<uint2*>(slc + (lin ^ lswz)) = w;
        }

    // ---------- QK^T swapped: sc[mi][nj] = K_nj x Q_mi -> D[j][m], lane owns row m=mi*16+ln ----------
    f32x4 sc[4][4];
    #pragma unroll
    for (int mi = 0; mi < 4; ++mi)
        #pragma unroll
        for (int nj = 0; nj < 4; ++nj)
            sc[mi][nj] = MFMA16(bk[nj], aq[mi], ((f32x4){0.f,0.f,0.f,0.f}));

    // bias base: idx = A0 + 30*(nj-mi) + r, addr = peg + 4*idx (immediate offsets after unroll)
    const char* bp = lds + PEG_OFF - 360 +
        4 * ((((lg >> 1) - (ln >> 3) + 7) * 15) + (lg & 1) * 4 - (ln & 7) + 7);

    float pinv[4];
    bf16x8 ap[4][2];
    #pragma unroll
    for (int mi = 0; mi < 4; ++mi) {
        #pragma unroll
        for (int nj = 0; nj < 4; ++nj)
            #pragma unroll
            for (int r = 0; r < 4; ++r)
                sc[mi][nj][r] = fmaf(sc[mi][nj][r], SCALE,
                    *reinterpret_cast<const float*>(bp + 360 + 120 * (nj - mi) + 4 * r));
        float mx = sc[mi][0][0];
        #pragma unroll
        for (int nj = 0; nj < 4; ++nj)
            #pragma unroll
            for (int r = 0; r < 4; ++r) mx = fmaxf(mx, sc[mi][nj][r]);
        mx = fmaxf(mx, __shfl_xor(mx, 16));
        mx = fmaxf(mx, __shfl_xor(mx, 32));
        float sum = 0.f;
        #pragma unroll
        for (int nj = 0; nj < 4; ++nj)
            #pragma unroll
            for (int r = 0; r < 4; ++r) {
                float e = __expf(sc[mi][nj][r] - mx);
                sc[mi][nj][r] = e;
                sum += e;
            }
        sum += __shfl_xor(sum, 16);
        sum += __shfl_xor(sum, 32);
        pinv[mi] = 1.f / sum;
        // pack unnormalized P fragments (j permuted: slot (lg,e) = 32kkv+16(e>>2)+4lg+(e&3))
        #pragma unroll
        for (int kkv = 0; kkv < 2; ++kkv) {
            int4 t;
            t.x = (int)pkbf(sc[mi][2 * kkv][0],     sc[mi][2 * kkv][1]);
            t.y = (int)pkbf(sc[mi][2 * kkv][2],     sc[mi][2 * kkv][3]);
            t.z = (int)pkbf(sc[mi][2 * kkv + 1][0], sc[mi][2 * kkv + 1][1]);
            t.w = (int)pkbf(sc[mi][2 * kkv + 1][2], sc[mi][2 * kkv + 1][3]);
            ap[mi][kkv] = __builtin_bit_cast(bf16x8, t);
        }
    }

    // ---------- PV swapped: po[u][mi] = V^T x P^T -> D[d][m]; V rows j-permuted to match ap ----------
    f32x4 po[2][4];
    #pragma unroll
    for (int u = 0; u < 2; ++u)
        #pragma unroll
        for (int mi = 0; mi < 4; ++mi) po[u][mi] = (f32x4){0.f,0.f,0.f,0.f};
    #pragma unroll
    for (int kkv = 0; kkv < 2; ++kkv) {
        bf16x8 bvf[2];
        #pragma unroll
        for (int u = 0; u < 2; ++u) {
            int d = u * 16 + ln;
            int lin0 = d * 128 + kkv * 64 + lg * 8;
            uint2 lo = *reinterpret_cast<const uint2*>(slc + (lin0 ^ lswz));
            uint2 hi = *reinterpret_cast<const uint2*>(slc + ((lin0 + 32) ^ lswz));
            int4 t; t.x = (int)lo.x; t.y = (int)lo.y; t.z = (int)hi.x; t.w = (int)hi.y;
            bvf[u] = __builtin_bit_cast(bf16x8, t);
        }
        #pragma unroll
        for (int u = 0; u < 2; ++u)
            #pragma unroll
            for (int mi = 0; mi < 4; ++mi)
                po[u][mi] = MFMA16(bvf[u], ap[mi][kkv], po[u][mi]);
    }

    // ---------- ao -> slc+4096 [t][32d] (overlays k; bk consumed), normalized by pinv ----------
    #pragma unroll
    for (int u = 0; u < 2; ++u)
        #pragma unroll
        for (int mi = 0; mi < 4; ++mi) {
            int lin = (mi * 16 + ln) * 64 + u * 32 + lg * 8;
            uint2 w = make_uint2(pkbf(po[u][mi][0] * pinv[mi], po[u][mi][1] * pinv[mi]),
                                 pkbf(po[u][mi][2] * pinv[mi], po[u][mi][3] * pinv[mi]));
            *reinterpret_cast<uint2*>(slc + 4096 + (lin ^ lswz)) = w;
        }
    __syncthreads();   // all waves' attn_out visible

    // ---------- GEMM2: out[64][32 cols of this wave] = AO[64][256] @ Wout^T + b ----------
    f32x4 fo[4][2];
    #pragma unroll
    for (int mi = 0; mi < 4; ++mi)
        #pragma unroll
        for (int u = 0; u < 2; ++u) fo[mi][u] = (f32x4){0.f,0.f,0.f,0.f};
    float bo0 = bout[wave * 32 + ln];
    float bo1 = bout[wave * 32 + 16 + ln];

    #pragma unroll 1
    for (int hh = 0; hh < 8; ++hh) {
        const char* ahh = lds + hh * 8192 + 4096;
        bf16x8 aa[4];
        #pragma unroll
        for (int mi = 0; mi < 4; ++mi)
            aa[mi] = *reinterpret_cast<const bf16x8*>(ahh + ((((mi * 16 + ln) * 64) + lg * 16) ^ lswz));
        bf16x8 bb[2];
        #pragma unroll
        for (int u = 0; u < 2; ++u) {
            if constexpr (USE_WS) {
                bb[u] = *reinterpret_cast<const bf16x8*>(
                    wsb + WS_QKV_BYTES + ((wave * 2 + u) * 8 + hh) * 1024 + fl);
            } else {
                int oc = wave * 32 + u * 16 + ln;
                bb[u] = cvt8(wout + (size_t)oc * 256 + hh * 32 + lg * 8);
            }
        }
        #pragma unroll
        for (int mi = 0; mi < 4; ++mi)
            #pragma unroll
            for (int u = 0; u < 2; ++u)
                fo[mi][u] = MFMA16(aa[mi], bb[u], fo[mi][u]);
    }

    #pragma unroll
    for (int mi = 0; mi < 4; ++mi)
        #pragma unroll
        for (int r = 0; r < 4; ++r) {
            int t = mi * 16 + lg * 4 + r;
            float* op = out + base + (size_t)(((t >> 3) * 128 + (t & 7)) * 256);
            op[wave * 32 + ln]      = fo[mi][0][r] + bo0;
            op[wave * 32 + 16 + ln] = fo[mi][1][r] + bo1;
        }
}

extern "C" void kernel_launch(void* const* d_in, const int* in_sizes, int n_in,
                              void* d_out, int out_size, void* d_ws, size_t ws_size,
                              hipStream_t stream) {
    const float* x    = (const float*)d_in[0];
    const float* wqkv = (const float*)d_in[1];
    const float* peg  = (const float*)d_in[2];
    const float* wout = (const float*)d_in[3];
    const float* bout = (const float*)d_in[4];
    float* out = (float*)d_out;
    if (d_ws != nullptr && ws_size >= WS_TOTAL_BYTES) {
        hipLaunchKernelGGL(prep_kernel, dim3(128), dim3(256), 0, stream,
                           wqkv, wout, (char*)d_ws);
        hipLaunchKernelGGL((winattn_kernel<true>), dim3(2048), dim3(512), 0, stream,
                           x, wqkv, peg, wout, bout, out, (const char*)d_ws);
    } else {
        hipLaunchKernelGGL((winattn_kernel<false>), dim3(2048), dim3(512), 0, stream,
                           x, wqkv, peg, wout, bout, out, nullptr);
    }
}